// Round 16
// baseline (152.034 us; speedup 1.0000x reference)
//
#include <hip/hip_runtime.h>
#include <hip/hip_bf16.h>
#include <math.h>

#define NN 2048
#define CHAIN 512
#define KNN 30
#define LRK 10
#define NFIX 40
#define NSLOT 42
#define HPAD 132
#define AGPAD 260
#define NREL 1023

#define OUT_ROT 0
#define OUT_TRANS (NN*9)
#define OUT_BB (NN*9 + NN*3)

#define THREEFRY_PARTITIONABLE 1

__device__ __forceinline__ int xcd_swz(int b){ return ((b & 7) << 8) | (b >> 3); }

// ---------------- threefry2x32, key = (0, 42) ----------------
__device__ __forceinline__ unsigned rotl32(unsigned x, unsigned r){ return (x<<r)|(x>>(32u-r)); }

__device__ __forceinline__ void tf_block(unsigned &x0, unsigned &x1){
  const unsigned k0 = 0u, k1 = 42u, k2 = 0x1BD11BDAu ^ 0u ^ 42u;
  x0 += k0; x1 += k1;
#define TFR(a) x0 += x1; x1 = rotl32(x1,(a)); x1 ^= x0;
  TFR(13) TFR(15) TFR(26) TFR(6)   x0 += k1; x1 += k2 + 1u;
  TFR(17) TFR(29) TFR(16) TFR(24)  x0 += k2; x1 += k0 + 2u;
  TFR(13) TFR(15) TFR(26) TFR(6)   x0 += k0; x1 += k1 + 3u;
  TFR(17) TFR(29) TFR(16) TFR(24)  x0 += k1; x1 += k2 + 4u;
  TFR(13) TFR(15) TFR(26) TFR(6)   x0 += k2; x1 += k0 + 5u;
#undef TFR
}

__device__ __forceinline__ float gumbel_from_bits(unsigned bits){
  float f = __uint_as_float((bits >> 9) | 0x3f800000u) - 1.0f;
  const float tiny = 1.17549435e-38f;
  float u = fmaxf(tiny, f * (1.0f - tiny) + tiny);
  return -logf(-logf(u));
}

__device__ __forceinline__ float gumbel_at(unsigned p){
#if THREEFRY_PARTITIONABLE
  unsigned x0 = 0u, x1 = p;
  tf_block(x0, x1);
  return gumbel_from_bits(x0 ^ x1);
#else
  const unsigned HALF = (NN*(unsigned)NN)/2u;
  unsigned c0, c1; bool lo = p < HALF;
  if(lo){ c0 = p; c1 = p + HALF; } else { c0 = p - HALF; c1 = p; }
  tf_block(c0, c1);
  return gumbel_from_bits(lo ? c0 : c1);
#endif
}

// ---------------- K1: fused topk / prep (4 nodes) / Trel (R13 form) ------------
__global__ __launch_bounds__(256) void k_pretop(
    const float* __restrict__ rots, const float* __restrict__ trans,
    const float* __restrict__ nf, const float* __restrict__ Wa1,
    const float* __restrict__ Wv,
    const int* __restrict__ xmask, const int* __restrict__ nmask,
    float* __restrict__ P, float* __restrict__ U, float* __restrict__ V,
    int* __restrict__ srcs, float* __restrict__ Trel)
{
  __shared__ __align__(16) char smem[4*4*132*4];
  int bb = blockIdx.x, t = threadIdx.x;

  if(bb >= NN + 512){
    // ---------------- Trel role ----------------
    int r = (bb - (NN+512))*2 + (t >> 7);
    int k = t & 127;
    if(r < NREL){
      float rel = (float)(r - 511);
      float acc = 0.f;
#pragma unroll
      for(int j=0;j<8;j++){
        float fr = expf((float)(2*j) * (float)(-0.5756462732485115));
        float ang = rel * fr;
        acc += cosf(ang) * Wa1[(278+j)*128 + k];
        acc += sinf(ang) * Wa1[(286+j)*128 + k];
      }
      Trel[r*128 + k] = acc;
    }
    return;
  }

  if(bb < NN){
    // ---------------- topk role ----------------
    unsigned* s_kk = (unsigned*)smem;          // [512]
    unsigned* s_lk = s_kk + CHAIN;             // [512]
    int i = bb;
    int base = (i >> 9) << 9;
    float tx = trans[i*3+0], ty = trans[i*3+1], tz = trans[i*3+2];
    for(int q=t; q<CHAIN; q+=256){
      int j = base + q;
      float dx = __fsub_rn(trans[j*3+0], tx);
      float dy = __fsub_rn(trans[j*3+1], ty);
      float dz = __fsub_rn(trans[j*3+2], tz);
      float d2 = __fadd_rn(__fadd_rn(__fmul_rn(dx,dx),__fmul_rn(dy,dy)),__fmul_rn(dz,dz));
      bool val = (j != i);
      float dm = val ? d2 : 1e30f;
      s_kk[q] = __float_as_uint(dm) ^ 0x80000000u;
      if(val){
        float g = gumbel_at((unsigned)(i*NN + j));
        float sc = __fadd_rn(__fmul_rn(-1.5f, logf(dm)), g);
        unsigned b = __float_as_uint(sc);
        unsigned ord = b ^ ((b & 0x80000000u) ? 0xFFFFFFFFu : 0x80000000u);
        s_lk[q] = ~ord;
      } else {
        s_lk[q] = 0xFFFFFFFFu;
      }
    }
    __syncthreads();
    if(t < 128){
      int w = t >> 6, lane = t & 63;
      unsigned* arr = w ? s_lk : s_kk;
      int K = w ? LRK : KNN;
      int outoff = w ? KNN : 0;
      unsigned long long k0_ = ((unsigned long long)arr[lane      ]<<32) | (unsigned)(lane);
      unsigned long long k1_ = ((unsigned long long)arr[lane + 64 ]<<32) | (unsigned)(lane+64);
      unsigned long long k2_ = ((unsigned long long)arr[lane + 128]<<32) | (unsigned)(lane+128);
      unsigned long long k3_ = ((unsigned long long)arr[lane + 192]<<32) | (unsigned)(lane+192);
      unsigned long long k4_ = ((unsigned long long)arr[lane + 256]<<32) | (unsigned)(lane+256);
      unsigned long long k5_ = ((unsigned long long)arr[lane + 320]<<32) | (unsigned)(lane+320);
      unsigned long long k6_ = ((unsigned long long)arr[lane + 384]<<32) | (unsigned)(lane+384);
      unsigned long long k7_ = ((unsigned long long)arr[lane + 448]<<32) | (unsigned)(lane+448);
      unsigned long long lmin;
      {
        unsigned long long a01 = k0_<k1_?k0_:k1_, a23 = k2_<k3_?k2_:k3_;
        unsigned long long a45 = k4_<k5_?k4_:k5_, a67 = k6_<k7_?k6_:k7_;
        unsigned long long a03 = a01<a23?a01:a23, a47 = a45<a67?a45:a67;
        lmin = a03<a47?a03:a47;
      }
      for(int k=0;k<K;k++){
        unsigned long long r = lmin;
        for(int off=32; off; off>>=1){
          unsigned long long o = __shfl_xor(r, off, 64);
          if(o < r) r = o;
        }
        if(lane == 0) srcs[i*NFIX + outoff + k] = base + (int)(unsigned)(r & 0xffffffffull);
        if(r == lmin){
          if(k0_ == r) k0_ = ~0ull;
          if(k1_ == r) k1_ = ~0ull;
          if(k2_ == r) k2_ = ~0ull;
          if(k3_ == r) k3_ = ~0ull;
          if(k4_ == r) k4_ = ~0ull;
          if(k5_ == r) k5_ = ~0ull;
          if(k6_ == r) k6_ = ~0ull;
          if(k7_ == r) k7_ = ~0ull;
          unsigned long long a01 = k0_<k1_?k0_:k1_, a23 = k2_<k3_?k2_:k3_;
          unsigned long long a45 = k4_<k5_?k4_:k5_, a67 = k6_<k7_?k6_:k7_;
          unsigned long long a03 = a01<a23?a01:a23, a47 = a45<a67?a45:a67;
          lmin = a03<a47?a03:a47;
        }
      }
    }
    return;
  }

  // ---------------- prep role (4 nodes) ----------------
  float (*fr)[4][132] = (float (*)[4][132])smem;
  int n0 = (bb - NN)*4;
  for(int i=t; i<2048; i+=256){
    int nd = i>>9, c = (i>>7)&3, kk = i&127;
    fr[nd][c][kk] = nf[(n0+nd)*512 + c*128 + kk];
  }
  if(t < 4){
    fr[t][0][128] = 0.0f; fr[t][0][129] = 0.0f;
    fr[t][0][130] = (nmask[n0+t] != 0 && xmask[n0+t] == 0) ? 1.0f : 0.0f;
  } else if(t >= 16 && t < 52){
    int q = t - 16; int nd = q/9, r = q%9, a = r/3, i = r%3;
    int n = n0 + nd;
    const float BB[3][3] = {{-0.525f,1.363f,0.0f},{0.f,0.f,0.f},{1.526f,0.f,0.f}};
    float bb_ = rots[n*9+i*3+0]*BB[a][0] + rots[n*9+i*3+1]*BB[a][1]
              + rots[n*9+i*3+2]*BB[a][2] + trans[n*3+i];
    fr[nd][1+i][128+a] = bb_;
  }
  __syncthreads();

  float a[4][4];
#pragma unroll
  for(int nd=0;nd<4;nd++)
#pragma unroll
    for(int c=0;c<4;c++) a[nd][c]=0.f;
  for(int j=0;j<128;j+=4){
    float w0=Wv[(j+0)*256+t], w1=Wv[(j+1)*256+t], w2=Wv[(j+2)*256+t], w3=Wv[(j+3)*256+t];
#pragma unroll
    for(int nd=0;nd<4;nd++){
#pragma unroll
      for(int c=0;c<4;c++){
        float4 f4 = *(const float4*)&fr[nd][c][j];
        a[nd][c] += f4.x*w0 + f4.y*w1 + f4.z*w2 + f4.w*w3;
      }
    }
  }
  for(int j=128;j<131;j++){
    float w = Wv[j*256+t];
#pragma unroll
    for(int nd=0;nd<4;nd++)
#pragma unroll
      for(int c=0;c<4;c++) a[nd][c] += fr[nd][c][j]*w;
  }
#pragma unroll
  for(int nd=0;nd<4;nd++){
    float4 v4; v4.x=a[nd][0]; v4.y=a[nd][1]; v4.z=a[nd][2]; v4.w=a[nd][3];
    *(float4*)&P[(n0+nd)*1024 + t*4] = v4;   // layout [n][u][c]
  }

  int k = t & 127;
  int isV = t >> 7;
  const float* Wcol = Wa1 + (isV ? 131*128 : 0);
  float u[4] = {0.f,0.f,0.f,0.f};
  for(int j=0;j<128;j+=4){
    float w0=Wcol[(j+0)*128+k], w1=Wcol[(j+1)*128+k], w2=Wcol[(j+2)*128+k], w3=Wcol[(j+3)*128+k];
#pragma unroll
    for(int nd=0;nd<4;nd++){
      float4 f4 = *(const float4*)&fr[nd][0][j];
      u[nd] += f4.x*w0 + f4.y*w1 + f4.z*w2 + f4.w*w3;
    }
  }
  for(int j=128;j<131;j++){
    float w = Wcol[j*128+k];
#pragma unroll
    for(int nd=0;nd<4;nd++) u[nd] += fr[nd][0][j]*w;
  }
  float* OUT = isV ? V : U;
#pragma unroll
  for(int nd=0;nd<4;nd++) OUT[(n0+nd)*128 + k] = u[nd];
}

// ---------------- K3: 2 nodes SEQUENTIALLY per block (1024 blocks, all-resident) ----
// s_mux: rbf [0,672) (per rep) | Wa2^T [672,1728) (staged once).
// agg lives in the dead s_H region [0, 4*AGPAD).
__global__ __launch_bounds__(256) void k_attn(
    const float* __restrict__ trans, const float* __restrict__ Wa1,
    const float* __restrict__ ba1, const float* __restrict__ Wa2,
    const float* __restrict__ Wo,
    const float* __restrict__ U, const float* __restrict__ V,
    const float* __restrict__ P, const float* __restrict__ Trel,
    const int* __restrict__ srcs, float* __restrict__ Y)
{
  __shared__ int   s_src[NSLOT];
  __shared__ int   s_val[NSLOT];
  __shared__ float s_dist[NSLOT];
  __shared__ __align__(16) float s_H[NSLOT*HPAD];   // 22176 B (H; then agg[4][260])
  __shared__ __align__(16) float s_mux[1728];       // 6912 B
  __shared__ float s_att[NSLOT*8];

  int b = blockIdx.x, t = threadIdx.x;
  int k = t & 127, grp = t >> 7;

  // one-time: Wa2^T staging + rbf weight column (both d-independent)
  for(int i=t; i<1024; i+=256){
    int kk = i >> 3, h = i & 7;
    s_mux[672 + h*HPAD + kk] = Wa2[i];
  }
  float wreg[16];
#pragma unroll
  for(int f=0; f<16; f++) wreg[f] = Wa1[(262+f)*128 + k];

  for(int rep=0; rep<2; rep++){
    int d = xcd_swz(b + rep*1024);
    int pos = d & (CHAIN-1);

    // phase 0: edge meta (42 threads); other threads idle-cheap
    if(t < NSLOT){
      int src;
      if(t < NFIX)      src = srcs[d*NFIX + t];
      else if(t == NFIX) src = (pos > 0)       ? d-1 : d;
      else               src = (pos < CHAIN-1) ? d+1 : d;
      s_src[t] = src;
      float dx = trans[src*3+0]-trans[d*3+0];
      float dy = trans[src*3+1]-trans[d*3+1];
      float dz = trans[src*3+2]-trans[d*3+2];
      float dist = sqrtf(dx*dx + dy*dy + dz*dz + 1e-12f);
      s_dist[t] = dist;
      s_val[t] = (dist > 1e-3f) ? 1 : 0;
    }
    float ubias = ba1[k] + V[d*128 + k];
    __syncthreads();                      // sync A (meta ready; also rep-boundary fence)

    // phase 1: gather U/Trel -> s_H + rbf -> s_mux[0,672)
    for(int e = grp; e < NSLOT; e += 2){
      int src = s_src[e];
      s_H[e*HPAD + k] = U[src*128 + k] + Trel[(src - d + 511)*128 + k];
    }
    for(int i=t; i<NSLOT*16; i+=256){
      int e = i >> 4, f = i & 15;
      float zz = (s_dist[e] - (float)f * (20.0f/15.0f)) * 0.8f;
      s_mux[i] = expf(-(zz*zz));
    }
    __syncthreads();                      // sync B

    // phase 2: H = leaky(ubias + gathered + rbf.wreg)
    for(int e = grp; e < NSLOT; e += 2){
      float h = ubias + s_H[e*HPAD + k];
      const float4* rp = (const float4*)(s_mux + e*16);
#pragma unroll
      for(int q=0; q<4; q++){
        float4 ev = rp[q];
        h += ev.x*wreg[4*q+0] + ev.y*wreg[4*q+1] + ev.z*wreg[4*q+2] + ev.w*wreg[4*q+3];
      }
      h = (h >= 0.0f) ? h : 0.01f*h;
      s_H[e*HPAD + k] = h;
    }
    __syncthreads();                      // sync C

    // phase 3: logits[e][h] = H[e] . Wa2[:,h]
    for(int p = t; p < NSLOT*8; p += 256){
      int e = p >> 3, h = p & 7;
      const float4* Hp = (const float4*)(s_H + e*HPAD);
      const float4* Wp = (const float4*)(s_mux + 672 + h*HPAD);
      float acc = 0.f;
#pragma unroll
      for(int q=0; q<32; q++){
        float4 a = Hp[q], w = Wp[q];
        acc += a.x*w.x + a.y*w.y + a.z*w.z + a.w*w.w;
      }
      s_att[p] = s_val[e] ? acc : -1e30f;
    }
    __syncthreads();                      // sync D

    // phase 4: per-head softmax
    if(t < 64){
      int h = t & 7, g = t >> 3;
      float m = -INFINITY;
      for(int e=g; e<NSLOT; e+=8) m = fmaxf(m, s_att[e*8+h]);
      for(int off=8; off<64; off<<=1) m = fmaxf(m, __shfl_xor(m, off, 64));
      m = (m > -5e29f) ? m : 0.0f;
      float z = 0.0f;
      for(int e=g; e<NSLOT; e+=8){
        float p = expf(s_att[e*8+h] - m);
        s_att[e*8+h] = p; z += p;
      }
      for(int off=8; off<64; off<<=1) z += __shfl_xor(z, off, 64);
      float inv = 1.0f / (z + 1e-9f);
      for(int e=g; e<NSLOT; e+=8) s_att[e*8+h] *= inv;
    }
    __syncthreads();                      // sync E

    // phase 5: agg[u=t][c] -> s_H (H values dead after phase 3)
    {
      int h = t >> 5;
      float a0=0.f,a1=0.f,a2=0.f,a3=0.f;
      for(int e=0;e<NSLOT;e++){
        float w = s_att[e*8 + h];
        float4 p4 = *(const float4*)(P + (size_t)s_src[e]*1024 + t*4);
        a0 += w*p4.x; a1 += w*p4.y; a2 += w*p4.z; a3 += w*p4.w;
      }
      s_H[0*AGPAD + t] = a0;
      s_H[1*AGPAD + t] = a1;
      s_H[2*AGPAD + t] = a2;
      s_H[3*AGPAD + t] = a3;
    }
    __syncthreads();                      // sync F

    // phase 6: Y[d][c][k] = agg[c] @ Wo (coalesced weight loads)
    {
      int cp = grp*2;
      const float* g0 = s_H + cp*AGPAD;
      const float* g1 = s_H + (cp+1)*AGPAD;
      float x0=0.f, x1=0.f;
      for(int u=0; u<256; u+=4){
        float w0=Wo[(u+0)*128+k], w1=Wo[(u+1)*128+k], w2=Wo[(u+2)*128+k], w3=Wo[(u+3)*128+k];
        float4 a0 = *(const float4*)(g0 + u);
        float4 a1 = *(const float4*)(g1 + u);
        x0 += a0.x*w0 + a0.y*w1 + a0.z*w2 + a0.w*w3;
        x1 += a1.x*w0 + a1.y*w1 + a1.z*w2 + a1.w*w3;
      }
      Y[d*512 + cp*128 + k]     = x0;
      Y[d*512 + (cp+1)*128 + k] = x1;
    }
  }
}

// ---------------- K5: per-node MLP chain, 4 nodes/block, 512 threads (R13 form) ----
__global__ __launch_bounds__(512) void k_node(
    const float* __restrict__ rots, const float* __restrict__ trans,
    const float* __restrict__ Y,
    const float* __restrict__ Wg, const float* __restrict__ Wf1,
    const float* __restrict__ Wf2, const float* __restrict__ Wr1,
    const float* __restrict__ br1, const float* __restrict__ Wr2,
    const float* __restrict__ br2, const float* __restrict__ Wr3,
    const float* __restrict__ br3, const float* __restrict__ Wt,
    const int* __restrict__ nmask, float* __restrict__ out)
{
  __shared__ __align__(16) float s_y[4][4][128];
  __shared__ __align__(16) float s_t1[4][128];
  __shared__ __align__(16) float s_bb0[4][128];
  __shared__ __align__(16) float s_gv[4][3][128];
  __shared__ __align__(16) float s_h1[4][256];
  __shared__ __align__(16) float s_h2[4][128];
  __shared__ float s_sc[4][8];

  int b = blockIdx.x, t = threadIdx.x;
  int nd = t >> 7, k = t & 127;
  int dbase = b*4;
  int d = dbase + nd;
  for(int i=t; i<4*512; i+=512){
    int n2 = i>>9, c=(i>>7)&3, kk=i&127;
    s_y[n2][c][kk] = Y[(dbase+n2)*512 + c*128 + kk];
  }
  __syncthreads();

  float g=0.f, f1=0.f;
  for(int j=0;j<128;j+=4){
    float wg0=Wg[(j+0)*128+k], wg1=Wg[(j+1)*128+k], wg2=Wg[(j+2)*128+k], wg3=Wg[(j+3)*128+k];
    float wf0=Wf1[(j+0)*128+k], wf1_=Wf1[(j+1)*128+k], wf2_=Wf1[(j+2)*128+k], wf3=Wf1[(j+3)*128+k];
    float4 yv = *(const float4*)&s_y[nd][0][j];
    g  += yv.x*wg0 + yv.y*wg1 + yv.z*wg2 + yv.w*wg3;
    f1 += yv.x*wf0 + yv.y*wf1_ + yv.z*wf2_ + yv.w*wf3;
  }
  float gate = 1.0f/(1.0f + expf(-g));
  s_t1[nd][k] = fmaxf(f1, 0.0f);
  __syncthreads();

  float f0=0.f;
  for(int j=0;j<128;j+=4){
    float w0=Wf2[(j+0)*128+k], w1=Wf2[(j+1)*128+k], w2=Wf2[(j+2)*128+k], w3=Wf2[(j+3)*128+k];
    float4 tv = *(const float4*)&s_t1[nd][j];
    f0 += tv.x*w0 + tv.y*w1 + tv.z*w2 + tv.w*w3;
  }
  {
    float bb0 = s_y[nd][0][k] + f0;
    s_bb0[nd][k] = bb0;
    out[OUT_BB + d*512 + k] = bb0;
#pragma unroll
    for(int c=1;c<4;c++){
      float v = s_y[nd][c][k] * gate;
      s_gv[nd][c-1][k] = v;
      out[OUT_BB + d*512 + c*128 + k] = v;
    }
  }
  __syncthreads();

  float a1 = br1[k], a2 = br1[128+k];
  for(int j=0;j<128;j+=4){
    float w10=Wr1[(j+0)*256+k],     w11=Wr1[(j+1)*256+k],     w12=Wr1[(j+2)*256+k],     w13=Wr1[(j+3)*256+k];
    float w20=Wr1[(j+0)*256+128+k], w21=Wr1[(j+1)*256+128+k], w22=Wr1[(j+2)*256+128+k], w23=Wr1[(j+3)*256+128+k];
    float4 bv = *(const float4*)&s_bb0[nd][j];
    a1 += bv.x*w10 + bv.y*w11 + bv.z*w12 + bv.w*w13;
    a2 += bv.x*w20 + bv.y*w21 + bv.z*w22 + bv.w*w23;
  }
  s_h1[nd][k] = fmaxf(a1, 0.0f);
  s_h1[nd][128+k] = fmaxf(a2, 0.0f);
  __syncthreads();

  float a = br2[k];
  for(int j=0;j<256;j+=4){
    float w0=Wr2[(j+0)*128+k], w1=Wr2[(j+1)*128+k], w2=Wr2[(j+2)*128+k], w3=Wr2[(j+3)*128+k];
    float4 hv = *(const float4*)&s_h1[nd][j];
    a += hv.x*w0 + hv.y*w1 + hv.z*w2 + hv.w*w3;
  }
  s_h2[nd][k] = fmaxf(a, 0.0f);
  __syncthreads();

  if(t < 12){
    int n2 = t/3, r = t%3;
    float q = br3[r];
    for(int kk=0;kk<128;kk++) q += s_h2[n2][kk] * Wr3[kk*6 + r];
    s_sc[n2][r] = q;
  } else if(t >= 32 && t < 44){
    int q2 = t-32; int n2 = q2/3, i = q2%3;
    float s = 0.f;
    for(int kk=0;kk<128;kk++) s += s_gv[n2][i][kk] * Wt[kk];
    s_sc[n2][4+i] = s;
  }
  __syncthreads();

  if(t < 4){
    int d2 = dbase + t;
    int nz = nmask[d2];
    float q1=s_sc[t][0], q2=s_sc[t][1], q3=s_sc[t][2];
    float nrm = sqrtf(1.0f + q1*q1 + q2*q2 + q3*q3);
    float w=1.0f/nrm, x=q1/nrm, y=q2/nrm, z=q3/nrm;
    float Ru[3][3];
    Ru[0][0]=1.f-2.f*(y*y+z*z); Ru[0][1]=2.f*(x*y-w*z);     Ru[0][2]=2.f*(x*z+w*y);
    Ru[1][0]=2.f*(x*y+w*z);     Ru[1][1]=1.f-2.f*(x*x+z*z); Ru[1][2]=2.f*(y*z-w*x);
    Ru[2][0]=2.f*(x*z-w*y);     Ru[2][1]=2.f*(y*z+w*x);     Ru[2][2]=1.f-2.f*(x*x+y*y);
    for(int i=0;i<3;i++){
      for(int j=0;j<3;j++){
        float rv;
        if(nz){
          rv = rots[d2*9+i*3+0]*Ru[0][j] + rots[d2*9+i*3+1]*Ru[1][j] + rots[d2*9+i*3+2]*Ru[2][j];
        } else {
          rv = rots[d2*9+i*3+j];
        }
        out[OUT_ROT + d2*9 + i*3 + j] = rv;
      }
      float tv = trans[d2*3+i];
      out[OUT_TRANS + d2*3 + i] = nz ? (tv + s_sc[t][4+i]) : tv;
    }
  }
}

extern "C" void kernel_launch(void* const* d_in, const int* in_sizes, int n_in,
                              void* d_out, int out_size, void* d_ws, size_t ws_size,
                              hipStream_t stream)
{
  (void)in_sizes; (void)n_in; (void)out_size; (void)ws_size;
  const float* rots = (const float*)d_in[0];
  const float* trans = (const float*)d_in[1];
  const float* nf   = (const float*)d_in[2];
  const float* Wa1  = (const float*)d_in[3];
  const float* ba1  = (const float*)d_in[4];
  const float* Wa2  = (const float*)d_in[5];
  const float* Wv   = (const float*)d_in[6];
  const float* Wo   = (const float*)d_in[7];
  const float* Wg   = (const float*)d_in[8];
  const float* Wf1  = (const float*)d_in[9];
  const float* Wf2  = (const float*)d_in[10];
  const float* Wr1  = (const float*)d_in[11];
  const float* br1  = (const float*)d_in[12];
  const float* Wr2  = (const float*)d_in[13];
  const float* br2  = (const float*)d_in[14];
  const float* Wr3  = (const float*)d_in[15];
  const float* br3  = (const float*)d_in[16];
  const float* Wt   = (const float*)d_in[17];
  const int* xmask  = (const int*)d_in[19];
  const int* nmask  = (const int*)d_in[20];

  float* P = (float*)d_ws;                 // NN*1024 f32  (8 MB), layout [n][u][c]
  float* U = P + NN*1024;                  // NN*128       (1 MB)
  float* V = U + NN*128;                   // NN*128       (1 MB)
  int* srcs = (int*)(V + NN*128);          // NN*40 int    (320 KB)
  float* Y  = (float*)(srcs + NN*NFIX);    // NN*512 f32   (4 MB)
  float* Trel = Y + NN*512;                // 1023*128 f32 (0.52 MB)

  k_pretop<<<NN + 512 + 512, 256, 0, stream>>>(rots, trans, nf, Wa1, Wv,
                                               xmask, nmask, P, U, V, srcs, Trel);
  k_attn<<<NN/2, 256, 0, stream>>>(trans, Wa1, ba1, Wa2, Wo, U, V, P, Trel, srcs, Y);
  k_node<<<NN/4, 512, 0, stream>>>(rots, trans, Y, Wg, Wf1, Wf2,
                                   Wr1, br1, Wr2, br2, Wr3, br3, Wt,
                                   nmask, (float*)d_out);
}

// Round 17
// 138.166 us; speedup vs baseline: 1.1004x; 1.1004x over previous
//
#include <hip/hip_runtime.h>
#include <hip/hip_bf16.h>
#include <math.h>

#define NN 2048
#define CHAIN 512
#define KNN 30
#define LRK 10
#define NFIX 40
#define NSLOT 42
#define HPAD 132
#define AGPAD 260
#define NREL 1023

#define OUT_ROT 0
#define OUT_TRANS (NN*9)
#define OUT_BB (NN*9 + NN*3)

#define THREEFRY_PARTITIONABLE 1

__device__ __forceinline__ int xcd_swz(int b){ return ((b & 7) << 8) | (b >> 3); }

// ---------------- threefry2x32, key = (0, 42) ----------------
__device__ __forceinline__ unsigned rotl32(unsigned x, unsigned r){ return (x<<r)|(x>>(32u-r)); }

__device__ __forceinline__ void tf_block(unsigned &x0, unsigned &x1){
  const unsigned k0 = 0u, k1 = 42u, k2 = 0x1BD11BDAu ^ 0u ^ 42u;
  x0 += k0; x1 += k1;
#define TFR(a) x0 += x1; x1 = rotl32(x1,(a)); x1 ^= x0;
  TFR(13) TFR(15) TFR(26) TFR(6)   x0 += k1; x1 += k2 + 1u;
  TFR(17) TFR(29) TFR(16) TFR(24)  x0 += k2; x1 += k0 + 2u;
  TFR(13) TFR(15) TFR(26) TFR(6)   x0 += k0; x1 += k1 + 3u;
  TFR(17) TFR(29) TFR(16) TFR(24)  x0 += k1; x1 += k2 + 4u;
  TFR(13) TFR(15) TFR(26) TFR(6)   x0 += k2; x1 += k0 + 5u;
#undef TFR
}

__device__ __forceinline__ float gumbel_from_bits(unsigned bits){
  float f = __uint_as_float((bits >> 9) | 0x3f800000u) - 1.0f;
  const float tiny = 1.17549435e-38f;
  float u = fmaxf(tiny, f * (1.0f - tiny) + tiny);
  return -logf(-logf(u));
}

__device__ __forceinline__ float gumbel_at(unsigned p){
#if THREEFRY_PARTITIONABLE
  unsigned x0 = 0u, x1 = p;
  tf_block(x0, x1);
  return gumbel_from_bits(x0 ^ x1);
#else
  const unsigned HALF = (NN*(unsigned)NN)/2u;
  unsigned c0, c1; bool lo = p < HALF;
  if(lo){ c0 = p; c1 = p + HALF; } else { c0 = p - HALF; c1 = p; }
  tf_block(c0, c1);
  return gumbel_from_bits(lo ? c0 : c1);
#endif
}

// ---------------- K1: fused topk / prep / Trel (block-role split) ------------
__global__ __launch_bounds__(256) void k_pretop(
    const float* __restrict__ rots, const float* __restrict__ trans,
    const float* __restrict__ nf, const float* __restrict__ Wa1,
    const float* __restrict__ Wv,
    const int* __restrict__ xmask, const int* __restrict__ nmask,
    float* __restrict__ P, float* __restrict__ U, float* __restrict__ V,
    int* __restrict__ srcs, float* __restrict__ Trel)
{
  __shared__ __align__(16) char smem[4*4*132*4];
  int bb = blockIdx.x, t = threadIdx.x;

  if(bb >= NN + 512){
    // ---------------- Trel role ----------------
    int r = (bb - (NN+512))*2 + (t >> 7);
    int k = t & 127;
    if(r < NREL){
      float rel = (float)(r - 511);
      float acc = 0.f;
#pragma unroll
      for(int j=0;j<8;j++){
        float fr = expf((float)(2*j) * (float)(-0.5756462732485115));
        float ang = rel * fr;
        acc += cosf(ang) * Wa1[(278+j)*128 + k];
        acc += sinf(ang) * Wa1[(286+j)*128 + k];
      }
      Trel[r*128 + k] = acc;
    }
    return;
  }

  if(bb < NN){
    // ---------------- topk role ----------------
    unsigned* s_kk = (unsigned*)smem;          // [512]
    unsigned* s_lk = s_kk + CHAIN;             // [512]
    int i = bb;
    int base = (i >> 9) << 9;
    float tx = trans[i*3+0], ty = trans[i*3+1], tz = trans[i*3+2];
    for(int q=t; q<CHAIN; q+=256){
      int j = base + q;
      float dx = __fsub_rn(trans[j*3+0], tx);
      float dy = __fsub_rn(trans[j*3+1], ty);
      float dz = __fsub_rn(trans[j*3+2], tz);
      float d2 = __fadd_rn(__fadd_rn(__fmul_rn(dx,dx),__fmul_rn(dy,dy)),__fmul_rn(dz,dz));
      bool val = (j != i);
      float dm = val ? d2 : 1e30f;
      s_kk[q] = __float_as_uint(dm) ^ 0x80000000u;
      if(val){
        float g = gumbel_at((unsigned)(i*NN + j));
        float sc = __fadd_rn(__fmul_rn(-1.5f, logf(dm)), g);
        unsigned b = __float_as_uint(sc);
        unsigned ord = b ^ ((b & 0x80000000u) ? 0xFFFFFFFFu : 0x80000000u);
        s_lk[q] = ~ord;
      } else {
        s_lk[q] = 0xFFFFFFFFu;
      }
    }
    __syncthreads();
    if(t < 128){
      int w = t >> 6, lane = t & 63;
      unsigned* arr = w ? s_lk : s_kk;
      int K = w ? LRK : KNN;
      int outoff = w ? KNN : 0;
      unsigned long long k0_ = ((unsigned long long)arr[lane      ]<<32) | (unsigned)(lane);
      unsigned long long k1_ = ((unsigned long long)arr[lane + 64 ]<<32) | (unsigned)(lane+64);
      unsigned long long k2_ = ((unsigned long long)arr[lane + 128]<<32) | (unsigned)(lane+128);
      unsigned long long k3_ = ((unsigned long long)arr[lane + 192]<<32) | (unsigned)(lane+192);
      unsigned long long k4_ = ((unsigned long long)arr[lane + 256]<<32) | (unsigned)(lane+256);
      unsigned long long k5_ = ((unsigned long long)arr[lane + 320]<<32) | (unsigned)(lane+320);
      unsigned long long k6_ = ((unsigned long long)arr[lane + 384]<<32) | (unsigned)(lane+384);
      unsigned long long k7_ = ((unsigned long long)arr[lane + 448]<<32) | (unsigned)(lane+448);
      unsigned long long lmin;
      {
        unsigned long long a01 = k0_<k1_?k0_:k1_, a23 = k2_<k3_?k2_:k3_;
        unsigned long long a45 = k4_<k5_?k4_:k5_, a67 = k6_<k7_?k6_:k7_;
        unsigned long long a03 = a01<a23?a01:a23, a47 = a45<a67?a45:a67;
        lmin = a03<a47?a03:a47;
      }
      for(int k=0;k<K;k++){
        unsigned long long r = lmin;
        for(int off=32; off; off>>=1){
          unsigned long long o = __shfl_xor(r, off, 64);
          if(o < r) r = o;
        }
        if(lane == 0) srcs[i*NFIX + outoff + k] = base + (int)(unsigned)(r & 0xffffffffull);
        if(r == lmin){
          if(k0_ == r) k0_ = ~0ull;
          if(k1_ == r) k1_ = ~0ull;
          if(k2_ == r) k2_ = ~0ull;
          if(k3_ == r) k3_ = ~0ull;
          if(k4_ == r) k4_ = ~0ull;
          if(k5_ == r) k5_ = ~0ull;
          if(k6_ == r) k6_ = ~0ull;
          if(k7_ == r) k7_ = ~0ull;
          unsigned long long a01 = k0_<k1_?k0_:k1_, a23 = k2_<k3_?k2_:k3_;
          unsigned long long a45 = k4_<k5_?k4_:k5_, a67 = k6_<k7_?k6_:k7_;
          unsigned long long a03 = a01<a23?a01:a23, a47 = a45<a67?a45:a67;
          lmin = a03<a47?a03:a47;
        }
      }
    }
    return;
  }

  // ---------------- prep role (4 nodes) ----------------
  float (*fr)[4][132] = (float (*)[4][132])smem;
  int n0 = (bb - NN)*4;
  for(int i=t; i<2048; i+=256){
    int nd = i>>9, c = (i>>7)&3, kk = i&127;
    fr[nd][c][kk] = nf[(n0+nd)*512 + c*128 + kk];
  }
  if(t < 4){
    fr[t][0][128] = 0.0f; fr[t][0][129] = 0.0f;
    fr[t][0][130] = (nmask[n0+t] != 0 && xmask[n0+t] == 0) ? 1.0f : 0.0f;
  } else if(t >= 16 && t < 52){
    int q = t - 16; int nd = q/9, r = q%9, a = r/3, i = r%3;
    int n = n0 + nd;
    const float BB[3][3] = {{-0.525f,1.363f,0.0f},{0.f,0.f,0.f},{1.526f,0.f,0.f}};
    float bb_ = rots[n*9+i*3+0]*BB[a][0] + rots[n*9+i*3+1]*BB[a][1]
              + rots[n*9+i*3+2]*BB[a][2] + trans[n*3+i];
    fr[nd][1+i][128+a] = bb_;
  }
  __syncthreads();

  float a[4][4];
#pragma unroll
  for(int nd=0;nd<4;nd++)
#pragma unroll
    for(int c=0;c<4;c++) a[nd][c]=0.f;
  for(int j=0;j<128;j+=4){
    float w0=Wv[(j+0)*256+t], w1=Wv[(j+1)*256+t], w2=Wv[(j+2)*256+t], w3=Wv[(j+3)*256+t];
#pragma unroll
    for(int nd=0;nd<4;nd++){
#pragma unroll
      for(int c=0;c<4;c++){
        float4 f4 = *(const float4*)&fr[nd][c][j];
        a[nd][c] += f4.x*w0 + f4.y*w1 + f4.z*w2 + f4.w*w3;
      }
    }
  }
  for(int j=128;j<131;j++){
    float w = Wv[j*256+t];
#pragma unroll
    for(int nd=0;nd<4;nd++)
#pragma unroll
      for(int c=0;c<4;c++) a[nd][c] += fr[nd][c][j]*w;
  }
#pragma unroll
  for(int nd=0;nd<4;nd++){
    float4 v4; v4.x=a[nd][0]; v4.y=a[nd][1]; v4.z=a[nd][2]; v4.w=a[nd][3];
    *(float4*)&P[(n0+nd)*1024 + t*4] = v4;   // layout [n][u][c]
  }

  int k = t & 127;
  int isV = t >> 7;
  const float* Wcol = Wa1 + (isV ? 131*128 : 0);
  float u[4] = {0.f,0.f,0.f,0.f};
  for(int j=0;j<128;j+=4){
    float w0=Wcol[(j+0)*128+k], w1=Wcol[(j+1)*128+k], w2=Wcol[(j+2)*128+k], w3=Wcol[(j+3)*128+k];
#pragma unroll
    for(int nd=0;nd<4;nd++){
      float4 f4 = *(const float4*)&fr[nd][0][j];
      u[nd] += f4.x*w0 + f4.y*w1 + f4.z*w2 + f4.w*w3;
    }
  }
  for(int j=128;j<131;j++){
    float w = Wcol[j*128+k];
#pragma unroll
    for(int nd=0;nd<4;nd++) u[nd] += fr[nd][0][j]*w;
  }
  float* OUT = isV ? V : U;
#pragma unroll
  for(int nd=0;nd<4;nd++) OUT[(n0+nd)*128 + k] = u[nd];
}

// ---------------- K3: edge logits + softmax + agg + @Wo — 6-barrier schedule ----
// s_mux layout (1728 floats): [0,672) rbf -> later agg[4][260]; [672,1728) Wa2^T rows h*132
__global__ __launch_bounds__(256) void k_attn(
    const float* __restrict__ trans, const float* __restrict__ Wa1,
    const float* __restrict__ ba1, const float* __restrict__ Wa2,
    const float* __restrict__ Wo,
    const float* __restrict__ U, const float* __restrict__ V,
    const float* __restrict__ P, const float* __restrict__ Trel,
    const int* __restrict__ srcs, float* __restrict__ Y)
{
  __shared__ int   s_src[NSLOT];
  __shared__ int   s_val[NSLOT];
  __shared__ float s_dist[NSLOT];
  __shared__ __align__(16) float s_H[NSLOT*HPAD];   // 22176 B
  __shared__ __align__(16) float s_mux[1728];       // 6912 B
  __shared__ float s_att[NSLOT*8];

  int b = blockIdx.x, t = threadIdx.x;
  int d = xcd_swz(b);
  int pos = d & (CHAIN-1);
  int k = t & 127, grp = t >> 7;

  // ---- phase 0 (pre-sync1): edge meta + Wa2^T staging + per-thread reg loads ----
  if(t < NSLOT){
    int src;
    if(t < NFIX)      src = srcs[d*NFIX + t];
    else if(t == NFIX) src = (pos > 0)       ? d-1 : d;
    else               src = (pos < CHAIN-1) ? d+1 : d;
    s_src[t] = src;
    float dx = trans[src*3+0]-trans[d*3+0];
    float dy = trans[src*3+1]-trans[d*3+1];
    float dz = trans[src*3+2]-trans[d*3+2];
    float dist = sqrtf(dx*dx + dy*dy + dz*dz + 1e-12f);
    s_dist[t] = dist;
    s_val[t] = (dist > 1e-3f) ? 1 : 0;
  }
  for(int i=t; i<1024; i+=256){          // Wa2^T: depends on nothing in-kernel
    int kk = i >> 3, h = i & 7;
    s_mux[672 + h*HPAD + kk] = Wa2[i];
  }
  float wreg[16];
#pragma unroll
  for(int f=0; f<16; f++) wreg[f] = Wa1[(262+f)*128 + k];
  float ubias = ba1[k] + V[d*128 + k];
  __syncthreads();                        // sync1

  // ---- phase 1: gather U/Trel (42 global loads in flight) + rbf transcendentals ----
  for(int e = grp; e < NSLOT; e += 2){
    int src = s_src[e];
    s_H[e*HPAD + k] = U[src*128 + k] + Trel[(src - d + 511)*128 + k];
  }
  for(int i=t; i<NSLOT*16; i+=256){
    int e = i >> 4, f = i & 15;
    float zz = (s_dist[e] - (float)f * (20.0f/15.0f)) * 0.8f;
    s_mux[i] = expf(-(zz*zz));
  }
  __syncthreads();                        // sync2

  // ---- phase 2: H = leaky(ubias + gathered + rbf.wreg) ----
  for(int e = grp; e < NSLOT; e += 2){
    float h = ubias + s_H[e*HPAD + k];
    const float4* rp = (const float4*)(s_mux + e*16);
#pragma unroll
    for(int q=0; q<4; q++){
      float4 ev = rp[q];
      h += ev.x*wreg[4*q+0] + ev.y*wreg[4*q+1] + ev.z*wreg[4*q+2] + ev.w*wreg[4*q+3];
    }
    h = (h >= 0.0f) ? h : 0.01f*h;
    s_H[e*HPAD + k] = h;
  }
  __syncthreads();                        // sync3

  // ---- phase 3: logits[e][h] = H[e] . Wa2[:,h] ----
  for(int p = t; p < NSLOT*8; p += 256){
    int e = p >> 3, h = p & 7;
    const float4* Hp = (const float4*)(s_H + e*HPAD);
    const float4* Wp = (const float4*)(s_mux + 672 + h*HPAD);
    float acc = 0.f;
#pragma unroll
    for(int q=0; q<32; q++){
      float4 a = Hp[q], w = Wp[q];
      acc += a.x*w.x + a.y*w.y + a.z*w.z + a.w*w.w;
    }
    s_att[p] = s_val[e] ? acc : -1e30f;
  }
  __syncthreads();                        // sync4

  // ---- phase 4: per-head softmax ----
  if(t < 64){
    int h = t & 7, g = t >> 3;
    float m = -INFINITY;
    for(int e=g; e<NSLOT; e+=8) m = fmaxf(m, s_att[e*8+h]);
    for(int off=8; off<64; off<<=1) m = fmaxf(m, __shfl_xor(m, off, 64));
    m = (m > -5e29f) ? m : 0.0f;
    float z = 0.0f;
    for(int e=g; e<NSLOT; e+=8){
      float p = expf(s_att[e*8+h] - m);
      s_att[e*8+h] = p; z += p;
    }
    for(int off=8; off<64; off<<=1) z += __shfl_xor(z, off, 64);
    float inv = 1.0f / (z + 1e-9f);
    for(int e=g; e<NSLOT; e+=8) s_att[e*8+h] *= inv;
  }
  __syncthreads();                        // sync5

  // ---- phase 5: agg[u=t][c] gather (wa2t/rbf regions dead -> reuse as agg) ----
  {
    int h = t >> 5;
    float a0=0.f,a1=0.f,a2=0.f,a3=0.f;
    for(int e=0;e<NSLOT;e++){
      float w = s_att[e*8 + h];
      float4 p4 = *(const float4*)(P + (size_t)s_src[e]*1024 + t*4);
      a0 += w*p4.x; a1 += w*p4.y; a2 += w*p4.z; a3 += w*p4.w;
    }
    s_mux[0*AGPAD + t] = a0;
    s_mux[1*AGPAD + t] = a1;
    s_mux[2*AGPAD + t] = a2;
    s_mux[3*AGPAD + t] = a3;
  }
  __syncthreads();                        // sync6

  // ---- phase 6: Y[d][c][k] = agg[c] @ Wo (coalesced weight loads) ----
  {
    int cp = grp*2;
    const float* g0 = s_mux + cp*AGPAD;
    const float* g1 = s_mux + (cp+1)*AGPAD;
    float x0=0.f, x1=0.f;
    for(int u=0; u<256; u+=4){
      float w0=Wo[(u+0)*128+k], w1=Wo[(u+1)*128+k], w2=Wo[(u+2)*128+k], w3=Wo[(u+3)*128+k];
      float4 a0 = *(const float4*)(g0 + u);
      float4 a1 = *(const float4*)(g1 + u);
      x0 += a0.x*w0 + a0.y*w1 + a0.z*w2 + a0.w*w3;
      x1 += a1.x*w0 + a1.y*w1 + a1.z*w2 + a1.w*w3;
    }
    Y[d*512 + cp*128 + k]     = x0;
    Y[d*512 + (cp+1)*128 + k] = x1;
  }
}

// ---------------- K5: per-node MLP chain, 4 nodes/block, 512 threads ------------
__global__ __launch_bounds__(512) void k_node(
    const float* __restrict__ rots, const float* __restrict__ trans,
    const float* __restrict__ Y,
    const float* __restrict__ Wg, const float* __restrict__ Wf1,
    const float* __restrict__ Wf2, const float* __restrict__ Wr1,
    const float* __restrict__ br1, const float* __restrict__ Wr2,
    const float* __restrict__ br2, const float* __restrict__ Wr3,
    const float* __restrict__ br3, const float* __restrict__ Wt,
    const int* __restrict__ nmask, float* __restrict__ out)
{
  __shared__ __align__(16) float s_y[4][4][128];
  __shared__ __align__(16) float s_t1[4][128];
  __shared__ __align__(16) float s_bb0[4][128];
  __shared__ __align__(16) float s_gv[4][3][128];
  __shared__ __align__(16) float s_h1[4][256];
  __shared__ __align__(16) float s_h2[4][128];
  __shared__ float s_sc[4][8];

  int b = blockIdx.x, t = threadIdx.x;
  int nd = t >> 7, k = t & 127;
  int dbase = b*4;
  int d = dbase + nd;
  for(int i=t; i<4*512; i+=512){
    int n2 = i>>9, c=(i>>7)&3, kk=i&127;
    s_y[n2][c][kk] = Y[(dbase+n2)*512 + c*128 + kk];
  }
  __syncthreads();

  float g=0.f, f1=0.f;
  for(int j=0;j<128;j+=4){
    float wg0=Wg[(j+0)*128+k], wg1=Wg[(j+1)*128+k], wg2=Wg[(j+2)*128+k], wg3=Wg[(j+3)*128+k];
    float wf0=Wf1[(j+0)*128+k], wf1_=Wf1[(j+1)*128+k], wf2_=Wf1[(j+2)*128+k], wf3=Wf1[(j+3)*128+k];
    float4 yv = *(const float4*)&s_y[nd][0][j];
    g  += yv.x*wg0 + yv.y*wg1 + yv.z*wg2 + yv.w*wg3;
    f1 += yv.x*wf0 + yv.y*wf1_ + yv.z*wf2_ + yv.w*wf3;
  }
  float gate = 1.0f/(1.0f + expf(-g));
  s_t1[nd][k] = fmaxf(f1, 0.0f);
  __syncthreads();

  float f0=0.f;
  for(int j=0;j<128;j+=4){
    float w0=Wf2[(j+0)*128+k], w1=Wf2[(j+1)*128+k], w2=Wf2[(j+2)*128+k], w3=Wf2[(j+3)*128+k];
    float4 tv = *(const float4*)&s_t1[nd][j];
    f0 += tv.x*w0 + tv.y*w1 + tv.z*w2 + tv.w*w3;
  }
  {
    float bb0 = s_y[nd][0][k] + f0;
    s_bb0[nd][k] = bb0;
    out[OUT_BB + d*512 + k] = bb0;
#pragma unroll
    for(int c=1;c<4;c++){
      float v = s_y[nd][c][k] * gate;
      s_gv[nd][c-1][k] = v;
      out[OUT_BB + d*512 + c*128 + k] = v;
    }
  }
  __syncthreads();

  float a1 = br1[k], a2 = br1[128+k];
  for(int j=0;j<128;j+=4){
    float w10=Wr1[(j+0)*256+k],     w11=Wr1[(j+1)*256+k],     w12=Wr1[(j+2)*256+k],     w13=Wr1[(j+3)*256+k];
    float w20=Wr1[(j+0)*256+128+k], w21=Wr1[(j+1)*256+128+k], w22=Wr1[(j+2)*256+128+k], w23=Wr1[(j+3)*256+128+k];
    float4 bv = *(const float4*)&s_bb0[nd][j];
    a1 += bv.x*w10 + bv.y*w11 + bv.z*w12 + bv.w*w13;
    a2 += bv.x*w20 + bv.y*w21 + bv.z*w22 + bv.w*w23;
  }
  s_h1[nd][k] = fmaxf(a1, 0.0f);
  s_h1[nd][128+k] = fmaxf(a2, 0.0f);
  __syncthreads();

  float a = br2[k];
  for(int j=0;j<256;j+=4){
    float w0=Wr2[(j+0)*128+k], w1=Wr2[(j+1)*128+k], w2=Wr2[(j+2)*128+k], w3=Wr2[(j+3)*128+k];
    float4 hv = *(const float4*)&s_h1[nd][j];
    a += hv.x*w0 + hv.y*w1 + hv.z*w2 + hv.w*w3;
  }
  s_h2[nd][k] = fmaxf(a, 0.0f);
  __syncthreads();

  if(t < 12){
    int n2 = t/3, r = t%3;
    float q = br3[r];
    for(int kk=0;kk<128;kk++) q += s_h2[n2][kk] * Wr3[kk*6 + r];
    s_sc[n2][r] = q;
  } else if(t >= 32 && t < 44){
    int q2 = t-32; int n2 = q2/3, i = q2%3;
    float s = 0.f;
    for(int kk=0;kk<128;kk++) s += s_gv[n2][i][kk] * Wt[kk];
    s_sc[n2][4+i] = s;
  }
  __syncthreads();

  if(t < 4){
    int d2 = dbase + t;
    int nz = nmask[d2];
    float q1=s_sc[t][0], q2=s_sc[t][1], q3=s_sc[t][2];
    float nrm = sqrtf(1.0f + q1*q1 + q2*q2 + q3*q3);
    float w=1.0f/nrm, x=q1/nrm, y=q2/nrm, z=q3/nrm;
    float Ru[3][3];
    Ru[0][0]=1.f-2.f*(y*y+z*z); Ru[0][1]=2.f*(x*y-w*z);     Ru[0][2]=2.f*(x*z+w*y);
    Ru[1][0]=2.f*(x*y+w*z);     Ru[1][1]=1.f-2.f*(x*x+z*z); Ru[1][2]=2.f*(y*z-w*x);
    Ru[2][0]=2.f*(x*z-w*y);     Ru[2][1]=2.f*(y*z+w*x);     Ru[2][2]=1.f-2.f*(x*x+y*y);
    for(int i=0;i<3;i++){
      for(int j=0;j<3;j++){
        float rv;
        if(nz){
          rv = rots[d2*9+i*3+0]*Ru[0][j] + rots[d2*9+i*3+1]*Ru[1][j] + rots[d2*9+i*3+2]*Ru[2][j];
        } else {
          rv = rots[d2*9+i*3+j];
        }
        out[OUT_ROT + d2*9 + i*3 + j] = rv;
      }
      float tv = trans[d2*3+i];
      out[OUT_TRANS + d2*3 + i] = nz ? (tv + s_sc[t][4+i]) : tv;
    }
  }
}

extern "C" void kernel_launch(void* const* d_in, const int* in_sizes, int n_in,
                              void* d_out, int out_size, void* d_ws, size_t ws_size,
                              hipStream_t stream)
{
  (void)in_sizes; (void)n_in; (void)out_size; (void)ws_size;
  const float* rots = (const float*)d_in[0];
  const float* trans = (const float*)d_in[1];
  const float* nf   = (const float*)d_in[2];
  const float* Wa1  = (const float*)d_in[3];
  const float* ba1  = (const float*)d_in[4];
  const float* Wa2  = (const float*)d_in[5];
  const float* Wv   = (const float*)d_in[6];
  const float* Wo   = (const float*)d_in[7];
  const float* Wg   = (const float*)d_in[8];
  const float* Wf1  = (const float*)d_in[9];
  const float* Wf2  = (const float*)d_in[10];
  const float* Wr1  = (const float*)d_in[11];
  const float* br1  = (const float*)d_in[12];
  const float* Wr2  = (const float*)d_in[13];
  const float* br2  = (const float*)d_in[14];
  const float* Wr3  = (const float*)d_in[15];
  const float* br3  = (const float*)d_in[16];
  const float* Wt   = (const float*)d_in[17];
  const int* xmask  = (const int*)d_in[19];
  const int* nmask  = (const int*)d_in[20];

  float* P = (float*)d_ws;                 // NN*1024 f32  (8 MB), layout [n][u][c]
  float* U = P + NN*1024;                  // NN*128       (1 MB)
  float* V = U + NN*128;                   // NN*128       (1 MB)
  int* srcs = (int*)(V + NN*128);          // NN*40 int    (320 KB)
  float* Y  = (float*)(srcs + NN*NFIX);    // NN*512 f32   (4 MB)
  float* Trel = Y + NN*512;                // 1023*128 f32 (0.52 MB)

  k_pretop<<<NN + 512 + 512, 256, 0, stream>>>(rots, trans, nf, Wa1, Wv,
                                               xmask, nmask, P, U, V, srcs, Trel);
  k_attn<<<NN, 256, 0, stream>>>(trans, Wa1, ba1, Wa2, Wo, U, V, P, Trel, srcs, Y);
  k_node<<<NN/4, 512, 0, stream>>>(rots, trans, Y, Wg, Wf1, Wf2,
                                   Wr1, br1, Wr2, br2, Wr3, br3, Wt,
                                   nmask, (float*)d_out);
}